// Round 12
// baseline (403.338 us; speedup 1.0000x reference)
//
#include <hip/hip_runtime.h>
#include <math.h>

#define DIMC 384
#define NHD  6
#define HD   64
#define WSZ  14
#define NTOK 196
#define NWIN 200
#define NWH  1200
#define MWIN 39200
#define MX   32768
#define MLPD 1536

typedef short short8 __attribute__((ext_vector_type(8)));
typedef float f32x4 __attribute__((ext_vector_type(4)));
typedef float f32x16 __attribute__((ext_vector_type(16)));

__device__ __forceinline__ unsigned short f2bf(float f) {
  unsigned int u = __float_as_uint(f);
  u = (u + 0x7fffu + ((u >> 16) & 1u)) >> 16;
  return (unsigned short)u;
}
__device__ __forceinline__ unsigned int pkbf(float a, float b) {
  unsigned int r; asm("v_cvt_pk_bf16_f32 %0, %1, %2" : "=v"(r) : "v"(a), "v"(b)); return r;
}
// tanh-GELU (|err| <= ~3e-3 abs; well under tolerance here)
__device__ __forceinline__ float gelu_t(float x) {
  float z = 1.5957691216057308f * (x + 0.044715f * x * x * x);
  float e = __expf(z);
  float th = 1.f - 2.f * __builtin_amdgcn_rcpf(e + 1.f);
  return 0.5f * x * (1.f + th);
}

typedef const __attribute__((address_space(1))) unsigned int* gptr_t;
typedef __attribute__((address_space(3))) unsigned int* lptr_t;
__device__ __forceinline__ void gload16(const unsigned short* g, unsigned short* l) {
  __builtin_amdgcn_global_load_lds((gptr_t)(const void*)g, (lptr_t)(void*)l, 16, 0, 0);
}

// ---------- weight transpose + bf16 convert ----------
__global__ void wtrans_kernel(const float* __restrict__ in, unsigned short* __restrict__ out,
                              int K, int N) {
  int id = blockIdx.x * 256 + threadIdx.x;
  if (id >= K * N) return;
  int n = id / K, k = id - n * K;
  out[id] = f2bf(in[(size_t)k * N + n]);
}

// ---------- relcat x8: rows 0..26 = 8*relh, 27..53 = 8*relw, rest 0 ----------
__global__ void relprep_kernel(const float* __restrict__ relh, const float* __restrict__ relw,
                               unsigned short* __restrict__ relcat) {
  int id = blockIdx.x * 256 + threadIdx.x;
  if (id >= 64 * 64) return;
  int rc = id >> 6, d = id & 63;
  float v = 0.f;
  if (rc < 27) v = relh[rc * 64 + d] * 8.f;
  else if (rc < 54) v = relw[(rc - 27) * 64 + d] * 8.f;
  relcat[id] = f2bf(v);
}

// ---------- zero vT pad columns 196..207 ----------
__global__ void vpad_kernel(unsigned short* __restrict__ vT) {
  int id = blockIdx.x * 256 + threadIdx.x;
  if (id >= 76800 * 3) return;
  int row = id / 3, part = id - row * 3;
  *(int2*)(vT + (size_t)row * 208 + 196 + part * 4) = make_int2(0, 0);
}

// ---------- LN1 + window partition ----------
__global__ __launch_bounds__(64) void ln1win_kernel(const float* __restrict__ x,
    const float* __restrict__ w, const float* __restrict__ b, unsigned short* __restrict__ xw) {
  int t = blockIdx.x;
  int lane = threadIdx.x;
  int win = t / NTOK, p = t - win * NTOK;
  int bb = win / 25, rem = win - bb * 25;
  int wi = rem / 5, wj = rem - wi * 5;
  int i = p / WSZ, j = p - i * WSZ;
  int r = wi * WSZ + i, c = wj * WSZ + j;
  unsigned short* o = xw + (size_t)t * DIMC;
  if (r >= 64 || c >= 64) {
    #pragma unroll
    for (int q = 0; q < 6; q++) o[lane + q * 64] = 0;
    return;
  }
  const float* xr = x + (((size_t)bb * 64 + r) * 64 + c) * DIMC;
  float v[6]; float s = 0.f, s2 = 0.f;
  #pragma unroll
  for (int q = 0; q < 6; q++) { float f = xr[lane + q * 64]; v[q] = f; s += f; s2 += f * f; }
  #pragma unroll
  for (int off = 32; off; off >>= 1) { s += __shfl_xor(s, off); s2 += __shfl_xor(s2, off); }
  float mean = s * (1.f / DIMC);
  float var  = s2 * (1.f / DIMC) - mean * mean;
  float rstd = rsqrtf(var + 1e-5f);
  #pragma unroll
  for (int q = 0; q < 6; q++) {
    int d = lane + q * 64;
    o[d] = f2bf((v[q] - mean) * rstd * w[d] + b[d]);
  }
}

// ---------- LN2 ----------
__global__ __launch_bounds__(64) void ln2_kernel(const float* __restrict__ x2,
    const float* __restrict__ w, const float* __restrict__ b, unsigned short* __restrict__ h2) {
  int t = blockIdx.x; int lane = threadIdx.x;
  const float* xr = x2 + (size_t)t * DIMC;
  unsigned short* o = h2 + (size_t)t * DIMC;
  float v[6]; float s = 0.f, s2 = 0.f;
  #pragma unroll
  for (int q = 0; q < 6; q++) { float f = xr[lane + q * 64]; v[q] = f; s += f; s2 += f * f; }
  #pragma unroll
  for (int off = 32; off; off >>= 1) { s += __shfl_xor(s, off); s2 += __shfl_xor(s2, off); }
  float mean = s * (1.f / DIMC);
  float var  = s2 * (1.f / DIMC) - mean * mean;
  float rstd = rsqrtf(var + 1e-5f);
  #pragma unroll
  for (int q = 0; q < 6; q++) {
    int d = lane + q * 64;
    o[d] = f2bf((v[q] - mean) * rstd * w[d] + b[d]);
  }
}

// ---------- 256x256 8-phase bf16 MFMA GEMM (T2+T3+T4+T5), 512 threads, 8 waves ----------
// Wave = 128x64 output. BK=64. LDS = 2 buf x 2 half x (128x64) for A and B = 128 KB.
// Per K-tile: 4 phases {ds_read subtile || stage 1 half-tile -> bar -> 16 MFMA -> bar}.
// Staging: tile t stages (t+1).A at ph0/ph1 (idle buffer), (t+2).B at ph2/ph3 (after B reads).
// One vmcnt(4) per tile-end keeps the 2 newest B-stages in flight. LDS XOR-swizzle via
// pre-swizzled global source (both-sides rule).
template <int EPI>
__global__ __launch_bounds__(512) void gemm_kernel(
    const unsigned short* __restrict__ A, const unsigned short* __restrict__ WT,
    int Mrows, int Ncols, int Kd,
    const float* __restrict__ bias, const float* __restrict__ addin,
    float* __restrict__ outf, unsigned short* __restrict__ outb,
    unsigned short* __restrict__ outb2) {
  __shared__ __align__(16) unsigned short As[2][2][8192];
  __shared__ __align__(16) unsigned short Bs[2][2][8192];
  const int nwg = gridDim.x * gridDim.y;
  const int flat = blockIdx.y * gridDim.x + blockIdx.x;
  const int xcd = flat & 7, q_ = nwg >> 3, r_ = nwg & 7;
  const int wg = (xcd < r_ ? xcd * (q_ + 1) : r_ * (q_ + 1) + (xcd - r_) * q_) + (flat >> 3);
  const int bx = wg / gridDim.y, by = wg - bx * gridDim.y;
  const int row0 = bx * 256, col0 = by * 256;
  const int tid = threadIdx.x;
  const int l = tid & 63, wid = tid >> 6;
  const int wid_m = wid >> 2, wid_n = wid & 3;
  const int fr = l & 15, fq = l >> 4;
  const int rsw = (fr & 7) * 8;                      // read-side swizzle (shorts)
  const int ch = wid * 2;                            // this wave's 2 staging chunks
  const int scol = ((l & 7) * 8) ^ (l & 56);         // pre-swizzled global col (shorts)
  const unsigned short* ap = A + (size_t)row0 * Kd;
  const unsigned short* bp = WT + (size_t)col0 * Kd;
  const int nt = Kd >> 6;

  auto stageA = [&](int kt, int half) {
    #pragma unroll
    for (int j = 0; j < 2; j++) {
      int c = ch + j;
      gload16(ap + (size_t)(half * 128 + c * 8 + (l >> 3)) * Kd + kt * 64 + scol,
              &As[kt & 1][half][c * 512]);
    }
  };
  auto stageB = [&](int kt, int half) {
    #pragma unroll
    for (int j = 0; j < 2; j++) {
      int c = ch + j;
      gload16(bp + (size_t)(half * 128 + c * 8 + (l >> 3)) * Kd + kt * 64 + scol,
              &Bs[kt & 1][half][c * 512]);
    }
  };

  f32x4 acc[8][4] = {};
  short8 a[8], b01[4], b23[4];

  auto lda = [&](int buf, int rbase) {               // 8 ds_read_b128
    #pragma unroll
    for (int f = 0; f < 4; f++)
      #pragma unroll
      for (int kk = 0; kk < 2; kk++)
        a[f * 2 + kk] = *(const short8*)
            &As[buf][wid_m][((rbase + f) * 16 + fr) * 64 + ((kk * 32 + fq * 8) ^ rsw)];
  };
  auto ldb = [&](short8* bf, int buf, int cbase) {   // 4 ds_read_b128
    const int halfb = wid_n >> 1, rb = (wid_n & 1) * 64;
    #pragma unroll
    for (int f = 0; f < 2; f++)
      #pragma unroll
      for (int kk = 0; kk < 2; kk++)
        bf[f * 2 + kk] = *(const short8*)
            &Bs[buf][halfb][(rb + (cbase + f) * 16 + fr) * 64 + ((kk * 32 + fq * 8) ^ rsw)];
  };

#define MMA(bf, aset, bset)                                                               \
  __builtin_amdgcn_s_setprio(1);                                                          \
  _Pragma("unroll")                                                                       \
  for (int f = 0; f < 4; f++)                                                             \
    _Pragma("unroll")                                                                     \
    for (int g = 0; g < 2; g++)                                                           \
      _Pragma("unroll")                                                                   \
      for (int kk = 0; kk < 2; kk++)                                                      \
        acc[(aset) * 4 + f][(bset) * 2 + g] = __builtin_amdgcn_mfma_f32_16x16x32_bf16(    \
            bf[g * 2 + kk], a[f * 2 + kk], acc[(aset) * 4 + f][(bset) * 2 + g], 0, 0, 0); \
  __builtin_amdgcn_s_setprio(0);

#define FENCE asm volatile("" ::: "memory")
#define BAR   __builtin_amdgcn_s_barrier()

  // prologue: tile0 fully + tile1's B; vmcnt(4) leaves 1.B* in flight
  stageA(0, 0); stageA(0, 1); stageB(0, 0); stageB(0, 1);
  stageB(1, 0); stageB(1, 1);
  asm volatile("s_waitcnt vmcnt(4)" ::: "memory");
  BAR;
  for (int t = 0; t < nt; ++t) {
    const int buf = t & 1;
    // ph0: quadrant (a0-3 x b0-1)
    lda(buf, 0); ldb(b01, buf, 0);
    if (t + 1 < nt) stageA(t + 1, 0);
    FENCE; BAR;
    MMA(b01, 0, 0);
    FENCE; BAR;
    // ph1: (a0-3 x b2-3)
    ldb(b23, buf, 2);
    if (t + 1 < nt) stageA(t + 1, 1);
    FENCE; BAR;
    MMA(b23, 0, 1);
    FENCE; BAR;
    // ph2: (a4-7 x b2-3); B-halves of this buf fully read -> restage
    lda(buf, 4);
    if (t + 2 < nt) stageB(t + 2, 0);
    FENCE; BAR;
    MMA(b23, 1, 1);
    FENCE; BAR;
    // ph3: (a4-7 x b0-1)
    if (t + 2 < nt) stageB(t + 2, 1);
    FENCE; BAR;
    MMA(b01, 1, 0);
    if (t < nt - 2) asm volatile("s_waitcnt vmcnt(4)" ::: "memory");
    else            asm volatile("s_waitcnt vmcnt(0)" ::: "memory");
    BAR;
  }
#undef MMA
#undef FENCE
#undef BAR

  #pragma unroll
  for (int fi = 0; fi < 8; fi++) {
    const int gr = row0 + wid_m * 128 + fi * 16 + fr;
    if (gr >= Mrows) continue;
    int wv_ = 0, p = 0, valid = 1; size_t pixbase = 0;
    if (EPI == 0 || EPI == 1) { wv_ = gr / NTOK; p = gr - wv_ * NTOK; }
    if (EPI == 1) {
      int bb = wv_ / 25, rem2 = wv_ - bb * 25;
      int wi = rem2 / 5, wj = rem2 - wi * 5;
      int i = p / WSZ, j = p - i * WSZ;
      int rr = wi * WSZ + i, cc = wj * WSZ + j;
      valid = (rr < 64) && (cc < 64);
      pixbase = (((size_t)bb * 64 + rr) * 64 + cc) * DIMC;
    }
    #pragma unroll
    for (int fj = 0; fj < 4; fj++) {
      const int gcb = col0 + wid_n * 64 + fj * 16 + fq * 4;
      if (gcb >= Ncols) continue;
      f32x4 v = acc[fi][fj];
      float4 bv = *(const float4*)&bias[gcb];
      float t0 = v[0] + bv.x, t1 = v[1] + bv.y, t2 = v[2] + bv.z, t3 = v[3] + bv.w;
      if (EPI == 0) {
        int s = gcb / 384, rem = gcb - s * 384;
        int hh = rem >> 6, d0 = gcb & 63;
        int whh = wv_ * NHD + hh;
        if (s == 0) { t0 *= 0.125f; t1 *= 0.125f; t2 *= 0.125f; t3 *= 0.125f; }
        if (s < 2) {
          *(int2*)&outb[((size_t)s * NWH + whh) * (NTOK * 64) + p * 64 + d0] =
              make_int2((int)pkbf(t0, t1), (int)pkbf(t2, t3));
        } else {
          unsigned short* vb = outb2 + ((size_t)whh * 64 + d0) * 208 + p;
          vb[0] = f2bf(t0); vb[208] = f2bf(t1); vb[416] = f2bf(t2); vb[624] = f2bf(t3);
        }
      } else if (EPI == 1) {
        if (valid) {
          size_t idx = pixbase + gcb;
          float4 ad = *(const float4*)&addin[idx];
          *(float4*)&outf[idx] = make_float4(t0 + ad.x, t1 + ad.y, t2 + ad.z, t3 + ad.w);
        }
      } else if (EPI == 2) {
        *(int2*)&outb[(size_t)gr * MLPD + gcb] =
            make_int2((int)pkbf(gelu_t(t0), gelu_t(t1)), (int)pkbf(gelu_t(t2), gelu_t(t3)));
      } else {
        size_t idx = (size_t)gr * DIMC + gcb;
        float4 ad = *(const float4*)&addin[idx];
        *(float4*)&outf[idx] = make_float4(t0 + ad.x, t1 + ad.y, t2 + ad.z, t3 + ad.w);
      }
    }
  }
}

// ---------- 32x32 MFMA attention: in-register P, defer-max online softmax ----------
template <bool TAIL>
__device__ __forceinline__ void attn_chunk(
    int kk, int l31, int hi,
    const unsigned short* __restrict__ kg,
    const unsigned short* __restrict__ VT,
    const short8* qf, const short8* qrel,
    f32x16& olo, f32x16& ohi_, float& m_reg, float& s_run) {
  int key = kk * 32 + l31;
  int keyc = (TAIL && key > 195) ? 195 : key;
  f32x16 S = {};
  __builtin_amdgcn_s_setprio(1);
  #pragma unroll
  for (int m = 0; m < 4; m++) {
    short8 kf = *(const short8*)(kg + (size_t)keyc * 64 + m * 16 + hi * 8);
    S = __builtin_amdgcn_mfma_f32_32x32x16_bf16(kf, qf[m], S, 0, 0, 0);
  }
  {
    int ki = keyc / 14, kj = keyc - ki * 14;
    #pragma unroll
    for (int m2 = 0; m2 < 2; m2++) {
      short8 kh;
      #pragma unroll
      for (int j = 0; j < 8; j++) {
        int cc = m2 * 16 + hi * 8 + j;
        kh[j] = (short)((cc == ki || cc == 14 + kj) ? 0x3F80 : 0);
      }
      S = __builtin_amdgcn_mfma_f32_32x32x16_bf16(kh, qrel[m2], S, 0, 0, 0);
    }
  }
  __builtin_amdgcn_s_setprio(0);
  float pmax = -3e38f;
  #pragma unroll
  for (int r = 0; r < 16; r++) {
    if (TAIL) {
      int krow = kk * 32 + (r & 3) + 8 * (r >> 2) + 4 * hi;
      if (krow >= 196) S[r] = -3e38f;
    }
    pmax = fmaxf(pmax, S[r]);
  }
  pmax = fmaxf(pmax, __shfl_xor(pmax, 32));
  if (__any(pmax > m_reg + 8.f)) {
    float m_new = fmaxf(m_reg, pmax);
    float fac = __expf(m_reg - m_new);
    m_reg = m_new;
    s_run *= fac;
    #pragma unroll
    for (int r = 0; r < 16; r++) {
      int qr = (r & 3) + 8 * (r >> 2) + 4 * hi;
      float fr_ = __shfl(fac, qr);
      olo[r] *= fr_; ohi_[r] *= fr_;
    }
  }
  float psum = 0.f;
  #pragma unroll
  for (int r = 0; r < 16; r++) { S[r] = __expf(S[r] - m_reg); psum += S[r]; }
  s_run += psum;
  unsigned int pk[8];
  #pragma unroll
  for (int t = 0; t < 8; t++) pk[t] = pkbf(S[2 * t], S[2 * t + 1]);
  #pragma unroll
  for (int m2 = 0; m2 < 2; m2++) {
    int b_ = m2 * 4;
    unsigned int x0 = (unsigned int)__shfl_xor((int)pk[b_ + 0], 32);
    unsigned int x1 = (unsigned int)__shfl_xor((int)pk[b_ + 1], 32);
    unsigned int x2 = (unsigned int)__shfl_xor((int)pk[b_ + 2], 32);
    unsigned int x3 = (unsigned int)__shfl_xor((int)pk[b_ + 3], 32);
    unsigned int au[4];
    au[0] = hi ? x2 : pk[b_ + 0];
    au[1] = hi ? x3 : pk[b_ + 1];
    au[2] = hi ? pk[b_ + 2] : x0;
    au[3] = hi ? pk[b_ + 3] : x1;
    short8 pa; __builtin_memcpy(&pa, au, 16);
    int kb = kk * 32 + m2 * 16 + hi * 8;
    if (TAIL && kb > 208) kb = 208;
    short8 vblo = *(const short8*)&VT[l31 * 216 + kb];
    short8 vbhi = *(const short8*)&VT[(32 + l31) * 216 + kb];
    __builtin_amdgcn_s_setprio(1);
    olo  = __builtin_amdgcn_mfma_f32_32x32x16_bf16(pa, vblo, olo, 0, 0, 0);
    ohi_ = __builtin_amdgcn_mfma_f32_32x32x16_bf16(pa, vbhi, ohi_, 0, 0, 0);
    __builtin_amdgcn_s_setprio(0);
  }
}

__global__ __launch_bounds__(256) void attn32_kernel(
    const unsigned short* __restrict__ qk_g,
    const unsigned short* __restrict__ vT_g,
    const unsigned short* __restrict__ relcat,
    unsigned short* __restrict__ attnout) {
  __shared__ __align__(16) unsigned short VT[64 * 216];
  __shared__ __align__(16) unsigned short RELB[4][2048];
  const int wh = blockIdx.x;
  const int w = wh / NHD, h = wh - w * NHD;
  const int tid = threadIdx.x;
  const unsigned short* vrow = vT_g + (size_t)wh * 64 * 208;
  for (int e = tid; e < 64 * 27; e += 256) {
    int d = e / 27, c = e - d * 27;
    int4 val = {0, 0, 0, 0};
    if (c < 26) val = *(const int4*)(vrow + d * 208 + c * 8);
    *(int4*)&VT[d * 216 + c * 8] = val;
  }
  __syncthreads();
  const int l = tid & 63, wv = tid >> 6;
  const int l31 = l & 31, hi = l >> 5;
  unsigned short* RB = &RELB[wv][0];
  const unsigned short* qg = qk_g + (size_t)wh * (NTOK * 64);
  const unsigned short* kg = qk_g + (size_t)(NWH + wh) * (NTOK * 64);

  for (int tile = wv; tile < 7; tile += 4) {
    const int q0 = tile * 32;
    int qrow = q0 + l31; if (qrow > 195) qrow = 195;
    short8 qf[4];
    #pragma unroll
    for (int m = 0; m < 4; m++)
      qf[m] = *(const short8*)(qg + (size_t)qrow * 64 + m * 16 + hi * 8);
    #pragma unroll
    for (int rt = 0; rt < 2; rt++) {
      f32x16 cr = {};
      __builtin_amdgcn_s_setprio(1);
      #pragma unroll
      for (int m = 0; m < 4; m++) {
        short8 af = *(const short8*)(relcat + (rt * 32 + l31) * 64 + m * 16 + hi * 8);
        cr = __builtin_amdgcn_mfma_f32_32x32x16_bf16(af, qf[m], cr, 0, 0, 0);
      }
      __builtin_amdgcn_s_setprio(0);
      #pragma unroll
      for (int t = 0; t < 8; t++) {
        int rr = rt * 32 + ((2 * t) & 3) + 8 * (t >> 1) + 4 * hi;
        *(unsigned int*)&RB[l31 * 64 + rr] = pkbf(cr[2 * t], cr[2 * t + 1]);
      }
    }
    __builtin_amdgcn_wave_barrier();
    int qi = qrow / 14, qj = qrow - qi * 14;
    short8 qrel[2];
    #pragma unroll
    for (int m2 = 0; m2 < 2; m2++)
      #pragma unroll
      for (int j = 0; j < 8; j++) {
        int cc = m2 * 16 + hi * 8 + j;
        unsigned short vv = 0;
        if (cc < 14) vv = RB[l31 * 64 + (qi - cc + 13)];
        else if (cc < 28) vv = RB[l31 * 64 + 27 + (qj - (cc - 14) + 13)];
        qrel[m2][j] = (short)vv;
      }
    __builtin_amdgcn_wave_barrier();
    f32x16 olo = {}, ohi_ = {};
    float m_reg = -3e38f, s_run = 0.f;
    for (int kk = 0; kk < 6; kk++)
      attn_chunk<false>(kk, l31, hi, kg, VT, qf, qrel, olo, ohi_, m_reg, s_run);
    attn_chunk<true>(6, l31, hi, kg, VT, qf, qrel, olo, ohi_, m_reg, s_run);
    s_run += __shfl_xor(s_run, 32);
    float inv = 1.f / s_run;
    #pragma unroll
    for (int r = 0; r < 16; r++) {
      int qr = (r & 3) + 8 * (r >> 2) + 4 * hi;
      float ir = __shfl(inv, qr);
      int tok = q0 + qr;
      if (tok < 196) {
        size_t base = ((size_t)w * NTOK + tok) * DIMC + h * 64;
        attnout[base + l31] = f2bf(olo[r] * ir);
        attnout[base + 32 + l31] = f2bf(ohi_[r] * ir);
      }
    }
  }
}

extern "C" void kernel_launch(void* const* d_in, const int* in_sizes, int n_in,
                              void* d_out, int out_size, void* d_ws, size_t ws_size,
                              hipStream_t stream) {
  const float* x     = (const float*)d_in[0];
  const float* ln1w  = (const float*)d_in[1];
  const float* ln1b  = (const float*)d_in[2];
  const float* qkvw  = (const float*)d_in[3];
  const float* qkvb  = (const float*)d_in[4];
  const float* projw = (const float*)d_in[5];
  const float* projb = (const float*)d_in[6];
  const float* relh  = (const float*)d_in[7];
  const float* relw  = (const float*)d_in[8];
  const float* ln2w  = (const float*)d_in[9];
  const float* ln2b  = (const float*)d_in[10];
  const float* fc1w  = (const float*)d_in[11];
  const float* fc1b  = (const float*)d_in[12];
  const float* fc2w  = (const float*)d_in[13];
  const float* fc2b  = (const float*)d_in[14];

  // R0: xw bf16 (39424 rows padded) / x2 f32
  // R1: qk + vT bf16 / hidden bf16
  // R2: attno bf16 (39424 rows padded) / h2 bf16
  // R3: transposed bf16 weights, PADDED to 256-multiples of N, + relcat
  const size_t R0 = 0;
  const size_t R1 = R0 + 50331648;
  const size_t R2 = R1 + 100663296;
  const size_t R3 = R2 + 30408704;
  const size_t NEED = R3 + 4136960;
  if (ws_size < NEED) return;
  char* ws = (char*)d_ws;
  unsigned short* xw     = (unsigned short*)(ws + R0);
  float*          x2     = (float*)(ws + R0);
  unsigned short* qk_g   = (unsigned short*)(ws + R1);
  unsigned short* vT_g   = qk_g + (size_t)2 * NWH * NTOK * 64;
  unsigned short* hidden = (unsigned short*)(ws + R1);
  unsigned short* attno  = (unsigned short*)(ws + R2);
  unsigned short* h2     = (unsigned short*)(ws + R2);
  unsigned short* qkvwT  = (unsigned short*)(ws + R3);        // 1280*384
  unsigned short* projwT = qkvwT + 491520;                    // 512*384
  unsigned short* fc1wT  = projwT + 196608;                   // 1536*384
  unsigned short* fc2wT  = fc1wT + 589824;                    // 512*1536
  unsigned short* relcat = fc2wT + 786432;

  wtrans_kernel<<<1728, 256, 0, stream>>>(qkvw, qkvwT, 384, 1152);
  wtrans_kernel<<<576, 256, 0, stream>>>(projw, projwT, 384, 384);
  wtrans_kernel<<<2304, 256, 0, stream>>>(fc1w, fc1wT, 384, 1536);
  wtrans_kernel<<<2304, 256, 0, stream>>>(fc2w, fc2wT, 1536, 384);
  relprep_kernel<<<16, 256, 0, stream>>>(relh, relw, relcat);
  vpad_kernel<<<900, 256, 0, stream>>>(vT_g);
  ln1win_kernel<<<MWIN, 64, 0, stream>>>(x, ln1w, ln1b, xw);
  gemm_kernel<0><<<dim3(154, 5), 512, 0, stream>>>(xw, qkvwT, MWIN, 1152, 384, qkvb, nullptr, nullptr, qk_g, vT_g);
  attn32_kernel<<<NWH, 256, 0, stream>>>(qk_g, vT_g, relcat, attno);
  gemm_kernel<1><<<dim3(154, 2), 512, 0, stream>>>(attno, projwT, MWIN, 384, 384, projb, x, x2, nullptr, nullptr);
  ln2_kernel<<<MX, 64, 0, stream>>>(x2, ln2w, ln2b, h2);
  gemm_kernel<2><<<dim3(128, 6), 512, 0, stream>>>(h2, fc1wT, MX, 1536, 384, fc1b, nullptr, nullptr, hidden, nullptr);
  gemm_kernel<3><<<dim3(128, 2), 512, 0, stream>>>(hidden, fc2wT, MX, 384, 1536, fc2b, x2, (float*)d_out, nullptr, nullptr);
}

// Round 13
// 349.737 us; speedup vs baseline: 1.1533x; 1.1533x over previous
//
#include <hip/hip_runtime.h>
#include <math.h>

#define DIMC 384
#define NHD  6
#define HD   64
#define WSZ  14
#define NTOK 196
#define NWIN 200
#define NWH  1200
#define MWIN 39200
#define MX   32768
#define MLPD 1536

typedef short short8 __attribute__((ext_vector_type(8)));
typedef float f32x4 __attribute__((ext_vector_type(4)));
typedef float f32x16 __attribute__((ext_vector_type(16)));

__device__ __forceinline__ unsigned short f2bf(float f) {
  unsigned int u = __float_as_uint(f);
  u = (u + 0x7fffu + ((u >> 16) & 1u)) >> 16;
  return (unsigned short)u;
}
__device__ __forceinline__ unsigned int pkbf(float a, float b) {
  unsigned int r; asm("v_cvt_pk_bf16_f32 %0, %1, %2" : "=v"(r) : "v"(a), "v"(b)); return r;
}
// tanh-GELU (|err| <= ~3e-3 abs; well under tolerance here)
__device__ __forceinline__ float gelu_t(float x) {
  float z = 1.5957691216057308f * (x + 0.044715f * x * x * x);
  float e = __expf(z);
  float th = 1.f - 2.f * __builtin_amdgcn_rcpf(e + 1.f);
  return 0.5f * x * (1.f + th);
}

typedef const __attribute__((address_space(1))) unsigned int* gptr_t;
typedef __attribute__((address_space(3))) unsigned int* lptr_t;
__device__ __forceinline__ void gload16(const unsigned short* g, unsigned short* l) {
  __builtin_amdgcn_global_load_lds((gptr_t)(const void*)g, (lptr_t)(void*)l, 16, 0, 0);
}

// ---------- merged prep: 4x weight transpose + relcat + vT pad zero, one launch ----------
#define SEG0 442368          // qkvwT  (K=384,  N=1152)
#define SEG1 589824          // projwT (K=384,  N=384)
#define SEG2 1179648         // fc1wT  (K=384,  N=1536)
#define SEG3 1769472         // fc2wT  (K=1536, N=384)
#define SEG4 1773568         // relcat (4096)
#define SEG5 2003968         // vpad   (76800*3 int2 writes)
__global__ void prep_kernel(const float* __restrict__ qkvw, const float* __restrict__ projw,
                            const float* __restrict__ fc1w, const float* __restrict__ fc2w,
                            const float* __restrict__ relh, const float* __restrict__ relw,
                            unsigned short* __restrict__ qkvwT, unsigned short* __restrict__ projwT,
                            unsigned short* __restrict__ fc1wT, unsigned short* __restrict__ fc2wT,
                            unsigned short* __restrict__ relcat, unsigned short* __restrict__ vT) {
  int id = blockIdx.x * 256 + threadIdx.x;
  if (id < SEG0) {
    int n = id / 384, k = id - n * 384;
    qkvwT[id] = f2bf(qkvw[(size_t)k * 1152 + n]);
  } else if (id < SEG1) {
    id -= SEG0;
    int n = id / 384, k = id - n * 384;
    projwT[id] = f2bf(projw[(size_t)k * 384 + n]);
  } else if (id < SEG2) {
    id -= SEG1;
    int n = id / 384, k = id - n * 384;
    fc1wT[id] = f2bf(fc1w[(size_t)k * 1536 + n]);
  } else if (id < SEG3) {
    id -= SEG2;
    int n = id / 1536, k = id - n * 1536;
    fc2wT[id] = f2bf(fc2w[(size_t)k * 384 + n]);
  } else if (id < SEG4) {
    id -= SEG3;
    int rc = id >> 6, d = id & 63;
    float v = 0.f;
    if (rc < 27) v = relh[rc * 64 + d] * 8.f;
    else if (rc < 54) v = relw[(rc - 27) * 64 + d] * 8.f;
    relcat[id] = f2bf(v);
  } else if (id < SEG5) {
    id -= SEG4;
    int row = id / 3, part = id - row * 3;
    *(int2*)(vT + (size_t)row * 208 + 196 + part * 4) = make_int2(0, 0);
  }
}

// ---------- LN1 + window partition ----------
__global__ __launch_bounds__(64) void ln1win_kernel(const float* __restrict__ x,
    const float* __restrict__ w, const float* __restrict__ b, unsigned short* __restrict__ xw) {
  int t = blockIdx.x;
  int lane = threadIdx.x;
  int win = t / NTOK, p = t - win * NTOK;
  int bb = win / 25, rem = win - bb * 25;
  int wi = rem / 5, wj = rem - wi * 5;
  int i = p / WSZ, j = p - i * WSZ;
  int r = wi * WSZ + i, c = wj * WSZ + j;
  unsigned short* o = xw + (size_t)t * DIMC;
  if (r >= 64 || c >= 64) {
    #pragma unroll
    for (int q = 0; q < 6; q++) o[lane + q * 64] = 0;
    return;
  }
  const float* xr = x + (((size_t)bb * 64 + r) * 64 + c) * DIMC;
  float v[6]; float s = 0.f, s2 = 0.f;
  #pragma unroll
  for (int q = 0; q < 6; q++) { float f = xr[lane + q * 64]; v[q] = f; s += f; s2 += f * f; }
  #pragma unroll
  for (int off = 32; off; off >>= 1) { s += __shfl_xor(s, off); s2 += __shfl_xor(s2, off); }
  float mean = s * (1.f / DIMC);
  float var  = s2 * (1.f / DIMC) - mean * mean;
  float rstd = rsqrtf(var + 1e-5f);
  #pragma unroll
  for (int q = 0; q < 6; q++) {
    int d = lane + q * 64;
    o[d] = f2bf((v[q] - mean) * rstd * w[d] + b[d]);
  }
}

// ---------- LN2 ----------
__global__ __launch_bounds__(64) void ln2_kernel(const float* __restrict__ x2,
    const float* __restrict__ w, const float* __restrict__ b, unsigned short* __restrict__ h2) {
  int t = blockIdx.x; int lane = threadIdx.x;
  const float* xr = x2 + (size_t)t * DIMC;
  unsigned short* o = h2 + (size_t)t * DIMC;
  float v[6]; float s = 0.f, s2 = 0.f;
  #pragma unroll
  for (int q = 0; q < 6; q++) { float f = xr[lane + q * 64]; v[q] = f; s += f; s2 += f * f; }
  #pragma unroll
  for (int off = 32; off; off >>= 1) { s += __shfl_xor(s, off); s2 += __shfl_xor(s2, off); }
  float mean = s * (1.f / DIMC);
  float var  = s2 * (1.f / DIMC) - mean * mean;
  float rstd = rsqrtf(var + 1e-5f);
  #pragma unroll
  for (int q = 0; q < 6; q++) {
    int d = lane + q * 64;
    o[d] = f2bf((v[q] - mean) * rstd * w[d] + b[d]);
  }
}

// ---------- bf16 MFMA GEMM: 128x128, 3-buffer counted-vmcnt pipeline, swizzled LDS,
// XCD remap. (r11 best-known configuration.) ----------
template <int EPI>
__global__ __launch_bounds__(256) void gemm_kernel(
    const unsigned short* __restrict__ A, const unsigned short* __restrict__ WT,
    int Mrows, int Kd,
    const float* __restrict__ bias, const float* __restrict__ addin,
    float* __restrict__ outf, unsigned short* __restrict__ outb,
    unsigned short* __restrict__ outb2) {
  __shared__ unsigned short As[3][128 * 32];
  __shared__ unsigned short Bs[3][128 * 32];
  const int nwg = gridDim.x * gridDim.y;
  const int flat = blockIdx.y * gridDim.x + blockIdx.x;
  const int xcd = flat & 7, q_ = nwg >> 3, r_ = nwg & 7;
  const int wg = (xcd < r_ ? xcd * (q_ + 1) : r_ * (q_ + 1) + (xcd - r_) * q_) + (flat >> 3);
  const int bx = wg / gridDim.y, by = wg - bx * gridDim.y;
  const int row0 = bx * 128, col0 = by * 128;
  const int tid = threadIdx.x;
  const int l = tid & 63, wid = tid >> 6;
  const int fr = l & 15, fk = (l >> 4) * 8;
  const int wr = (wid >> 1) * 64, wc = (wid & 1) * 64;
  const int sr = l >> 2, sc = (l & 3) * 8;
  const int scs = sc ^ (((sr >> 1) & 3) << 3);
  const int rsw = ((fr >> 1) & 3) << 3;
  f32x4 acc[4][4] = {};
  const unsigned short* ap = A + (size_t)row0 * Kd;
  const unsigned short* bp = WT + (size_t)col0 * Kd;
  const int nt = Kd >> 5;

  auto stage = [&](int t, int b) {
    const int k0 = t * 32;
    #pragma unroll
    for (int j = 0; j < 2; j++) {
      int chunk = j * 4 + wid;
      gload16(ap + (size_t)(chunk * 16 + sr) * Kd + k0 + scs, &As[b][chunk * 512]);
      gload16(bp + (size_t)(chunk * 16 + sr) * Kd + k0 + scs, &Bs[b][chunk * 512]);
    }
  };
  stage(0, 0);
  stage(1, 1);
  int c = 0;
  for (int t = 0; t < nt; ++t) {
    if (t < nt - 1) asm volatile("s_waitcnt vmcnt(4)" ::: "memory");
    else            asm volatile("s_waitcnt vmcnt(0)" ::: "memory");
    __builtin_amdgcn_s_barrier();
    __builtin_amdgcn_sched_barrier(0);
    if (t + 2 < nt) stage(t + 2, (c + 2 >= 3) ? c - 1 : c + 2);
    short8 a[4], b[4];
    #pragma unroll
    for (int fi = 0; fi < 4; fi++) {
      a[fi] = *(const short8*)&As[c][(wr + fi * 16 + fr) * 32 + (fk ^ rsw)];
      b[fi] = *(const short8*)&Bs[c][(wc + fi * 16 + fr) * 32 + (fk ^ rsw)];
    }
    __builtin_amdgcn_s_setprio(1);
    #pragma unroll
    for (int fi = 0; fi < 4; fi++)
      #pragma unroll
      for (int fj = 0; fj < 4; fj++)
        acc[fi][fj] = __builtin_amdgcn_mfma_f32_16x16x32_bf16(b[fj], a[fi], acc[fi][fj], 0, 0, 0);
    __builtin_amdgcn_s_setprio(0);
    c = (c + 1 >= 3) ? 0 : c + 1;
  }
  #pragma unroll
  for (int fi = 0; fi < 4; fi++) {
    const int gr = row0 + wr + fi * 16 + fr;
    if (gr >= Mrows) continue;
    int wv_ = 0, p = 0, valid = 1; size_t pixbase = 0;
    if (EPI == 0 || EPI == 1) { wv_ = gr / NTOK; p = gr - wv_ * NTOK; }
    if (EPI == 1) {
      int bb = wv_ / 25, rem2 = wv_ - bb * 25;
      int wi = rem2 / 5, wj = rem2 - wi * 5;
      int i = p / WSZ, j = p - i * WSZ;
      int rr = wi * WSZ + i, cc = wj * WSZ + j;
      valid = (rr < 64) && (cc < 64);
      pixbase = (((size_t)bb * 64 + rr) * 64 + cc) * DIMC;
    }
    #pragma unroll
    for (int fj = 0; fj < 4; fj++) {
      const int gcb = col0 + wc + fj * 16 + (l >> 4) * 4;
      f32x4 v = acc[fi][fj];
      float4 bv = *(const float4*)&bias[gcb];
      float t0 = v[0] + bv.x, t1 = v[1] + bv.y, t2 = v[2] + bv.z, t3 = v[3] + bv.w;
      if (EPI == 0) {
        int s = gcb / 384, rem = gcb - s * 384;
        int hh = rem >> 6, d0 = gcb & 63;
        int whh = wv_ * NHD + hh;
        if (s == 0) { t0 *= 0.125f; t1 *= 0.125f; t2 *= 0.125f; t3 *= 0.125f; }
        if (s < 2) {
          *(int2*)&outb[((size_t)s * NWH + whh) * (NTOK * 64) + p * 64 + d0] =
              make_int2((int)pkbf(t0, t1), (int)pkbf(t2, t3));
        } else {
          unsigned short* vb = outb2 + ((size_t)whh * 64 + d0) * 208 + p;
          vb[0] = f2bf(t0); vb[208] = f2bf(t1); vb[416] = f2bf(t2); vb[624] = f2bf(t3);
        }
      } else if (EPI == 1) {
        if (valid) {
          size_t idx = pixbase + gcb;
          float4 ad = *(const float4*)&addin[idx];
          *(float4*)&outf[idx] = make_float4(t0 + ad.x, t1 + ad.y, t2 + ad.z, t3 + ad.w);
        }
      } else if (EPI == 2) {
        *(int2*)&outb[(size_t)gr * MLPD + gcb] =
            make_int2((int)pkbf(gelu_t(t0), gelu_t(t1)), (int)pkbf(gelu_t(t2), gelu_t(t3)));
      } else {
        size_t idx = (size_t)gr * DIMC + gcb;
        float4 ad = *(const float4*)&addin[idx];
        *(float4*)&outf[idx] = make_float4(t0 + ad.x, t1 + ad.y, t2 + ad.z, t3 + ad.w);
      }
    }
  }
}

// ---------- 32x32 MFMA attention: in-register P, defer-max online softmax ----------
template <bool TAIL>
__device__ __forceinline__ void attn_chunk(
    int kk, int l31, int hi,
    const unsigned short* __restrict__ kg,
    const unsigned short* __restrict__ VT,
    const short8* qf, const short8* qrel,
    f32x16& olo, f32x16& ohi_, float& m_reg, float& s_run) {
  int key = kk * 32 + l31;
  int keyc = (TAIL && key > 195) ? 195 : key;
  f32x16 S = {};
  __builtin_amdgcn_s_setprio(1);
  #pragma unroll
  for (int m = 0; m < 4; m++) {
    short8 kf = *(const short8*)(kg + (size_t)keyc * 64 + m * 16 + hi * 8);
    S = __builtin_amdgcn_mfma_f32_32x32x16_bf16(kf, qf[m], S, 0, 0, 0);
  }
  {
    int ki = keyc / 14, kj = keyc - ki * 14;
    #pragma unroll
    for (int m2 = 0; m2 < 2; m2++) {
      short8 kh;
      #pragma unroll
      for (int j = 0; j < 8; j++) {
        int cc = m2 * 16 + hi * 8 + j;
        kh[j] = (short)((cc == ki || cc == 14 + kj) ? 0x3F80 : 0);
      }
      S = __builtin_amdgcn_mfma_f32_32x32x16_bf16(kh, qrel[m2], S, 0, 0, 0);
    }
  }
  __builtin_amdgcn_s_setprio(0);
  float pmax = -3e38f;
  #pragma unroll
  for (int r = 0; r < 16; r++) {
    if (TAIL) {
      int krow = kk * 32 + (r & 3) + 8 * (r >> 2) + 4 * hi;
      if (krow >= 196) S[r] = -3e38f;
    }
    pmax = fmaxf(pmax, S[r]);
  }
  pmax = fmaxf(pmax, __shfl_xor(pmax, 32));
  if (__any(pmax > m_reg + 8.f)) {
    float m_new = fmaxf(m_reg, pmax);
    float fac = __expf(m_reg - m_new);
    m_reg = m_new;
    s_run *= fac;
    #pragma unroll
    for (int r = 0; r < 16; r++) {
      int qr = (r & 3) + 8 * (r >> 2) + 4 * hi;
      float fr_ = __shfl(fac, qr);
      olo[r] *= fr_; ohi_[r] *= fr_;
    }
  }
  float psum = 0.f;
  #pragma unroll
  for (int r = 0; r < 16; r++) { S[r] = __expf(S[r] - m_reg); psum += S[r]; }
  s_run += psum;
  unsigned int pk[8];
  #pragma unroll
  for (int t = 0; t < 8; t++) pk[t] = pkbf(S[2 * t], S[2 * t + 1]);
  #pragma unroll
  for (int m2 = 0; m2 < 2; m2++) {
    int b_ = m2 * 4;
    unsigned int x0 = (unsigned int)__shfl_xor((int)pk[b_ + 0], 32);
    unsigned int x1 = (unsigned int)__shfl_xor((int)pk[b_ + 1], 32);
    unsigned int x2 = (unsigned int)__shfl_xor((int)pk[b_ + 2], 32);
    unsigned int x3 = (unsigned int)__shfl_xor((int)pk[b_ + 3], 32);
    unsigned int au[4];
    au[0] = hi ? x2 : pk[b_ + 0];
    au[1] = hi ? x3 : pk[b_ + 1];
    au[2] = hi ? pk[b_ + 2] : x0;
    au[3] = hi ? pk[b_ + 3] : x1;
    short8 pa; __builtin_memcpy(&pa, au, 16);
    int kb = kk * 32 + m2 * 16 + hi * 8;
    if (TAIL && kb > 208) kb = 208;
    short8 vblo = *(const short8*)&VT[l31 * 216 + kb];
    short8 vbhi = *(const short8*)&VT[(32 + l31) * 216 + kb];
    __builtin_amdgcn_s_setprio(1);
    olo  = __builtin_amdgcn_mfma_f32_32x32x16_bf16(pa, vblo, olo, 0, 0, 0);
    ohi_ = __builtin_amdgcn_mfma_f32_32x32x16_bf16(pa, vbhi, ohi_, 0, 0, 0);
    __builtin_amdgcn_s_setprio(0);
  }
}

__global__ __launch_bounds__(256) void attn32_kernel(
    const unsigned short* __restrict__ qk_g,
    const unsigned short* __restrict__ vT_g,
    const unsigned short* __restrict__ relcat,
    unsigned short* __restrict__ attnout) {
  __shared__ __align__(16) unsigned short VT[64 * 216];
  __shared__ __align__(16) unsigned short RELB[4][2048];
  const int wh = blockIdx.x, y = blockIdx.y;
  const int w = wh / NHD, h = wh - w * NHD;
  const int tid = threadIdx.x;
  const unsigned short* vrow = vT_g + (size_t)wh * 64 * 208;
  for (int e = tid; e < 64 * 27; e += 256) {
    int d = e / 27, c = e - d * 27;
    int4 val = {0, 0, 0, 0};
    if (c < 26) val = *(const int4*)(vrow + d * 208 + c * 8);
    *(int4*)&VT[d * 216 + c * 8] = val;
  }
  __syncthreads();
  const int l = tid & 63, wv = tid >> 6;
  const int l31 = l & 31, hi = l >> 5;
  unsigned short* RB = &RELB[wv][0];
  const unsigned short* qg = qk_g + (size_t)wh * (NTOK * 64);
  const unsigned short* kg = qk_g + (size_t)(NWH + wh) * (NTOK * 64);

  const int tbeg = y ? 4 : 0, tend = y ? 7 : 4;
  for (int tile = tbeg + wv; tile < tend; tile += 4) {
    const int q0 = tile * 32;
    int qrow = q0 + l31; if (qrow > 195) qrow = 195;
    short8 qf[4];
    #pragma unroll
    for (int m = 0; m < 4; m++)
      qf[m] = *(const short8*)(qg + (size_t)qrow * 64 + m * 16 + hi * 8);
    #pragma unroll
    for (int rt = 0; rt < 2; rt++) {
      f32x16 cr = {};
      __builtin_amdgcn_s_setprio(1);
      #pragma unroll
      for (int m = 0; m < 4; m++) {
        short8 af = *(const short8*)(relcat + (rt * 32 + l31) * 64 + m * 16 + hi * 8);
        cr = __builtin_amdgcn_mfma_f32_32x32x16_bf16(af, qf[m], cr, 0, 0, 0);
      }
      __builtin_amdgcn_s_setprio(0);
      #pragma unroll
      for (int t = 0; t < 8; t++) {
        int rr = rt * 32 + ((2 * t) & 3) + 8 * (t >> 1) + 4 * hi;
        *(unsigned int*)&RB[l31 * 64 + rr] = pkbf(cr[2 * t], cr[2 * t + 1]);
      }
    }
    __builtin_amdgcn_wave_barrier();
    int qi = qrow / 14, qj = qrow - qi * 14;
    short8 qrel[2];
    #pragma unroll
    for (int m2 = 0; m2 < 2; m2++)
      #pragma unroll
      for (int j = 0; j < 8; j++) {
        int cc = m2 * 16 + hi * 8 + j;
        unsigned short vv = 0;
        if (cc < 14) vv = RB[l31 * 64 + (qi - cc + 13)];
        else if (cc < 28) vv = RB[l31 * 64 + 27 + (qj - (cc - 14) + 13)];
        qrel[m2][j] = (short)vv;
      }
    __builtin_amdgcn_wave_barrier();
    f32x16 olo = {}, ohi_ = {};
    float m_reg = -3e38f, s_run = 0.f;
    for (int kk = 0; kk < 6; kk++)
      attn_chunk<false>(kk, l31, hi, kg, VT, qf, qrel, olo, ohi_, m_reg, s_run);
    attn_chunk<true>(6, l31, hi, kg, VT, qf, qrel, olo, ohi_, m_reg, s_run);
    s_run += __shfl_xor(s_run, 32);
    float inv = 1.f / s_run;
    #pragma unroll
    for (int r = 0; r < 16; r++) {
      int qr = (r & 3) + 8 * (r >> 2) + 4 * hi;
      float ir = __shfl(inv, qr);
      int tok = q0 + qr;
      if (tok < 196) {
        size_t base = ((size_t)w * NTOK + tok) * DIMC + h * 64;
        attnout[base + l31] = f2bf(olo[r] * ir);
        attnout[base + 32 + l31] = f2bf(ohi_[r] * ir);
      }
    }
  }
}

extern "C" void kernel_launch(void* const* d_in, const int* in_sizes, int n_in,
                              void* d_out, int out_size, void* d_ws, size_t ws_size,
                              hipStream_t stream) {
  const float* x     = (const float*)d_in[0];
  const float* ln1w  = (const float*)d_in[1];
  const float* ln1b  = (const float*)d_in[2];
  const float* qkvw  = (const float*)d_in[3];
  const float* qkvb  = (const float*)d_in[4];
  const float* projw = (const float*)d_in[5];
  const float* projb = (const float*)d_in[6];
  const float* relh  = (const float*)d_in[7];
  const float* relw  = (const float*)d_in[8];
  const float* ln2w  = (const float*)d_in[9];
  const float* ln2b  = (const float*)d_in[10];
  const float* fc1w  = (const float*)d_in[11];
  const float* fc1b  = (const float*)d_in[12];
  const float* fc2w  = (const float*)d_in[13];
  const float* fc2b  = (const float*)d_in[14];

  const size_t R0 = 0;
  const size_t R1 = R0 + 50331648;
  const size_t R2 = R1 + 100663296;
  const size_t R3 = R2 + 30408704;
  const size_t NEED = R3 + 3547136;
  if (ws_size < NEED) return;
  char* ws = (char*)d_ws;
  unsigned short* xw     = (unsigned short*)(ws + R0);
  float*          x2     = (float*)(ws + R0);
  unsigned short* qk_g   = (unsigned short*)(ws + R1);
  unsigned short* vT_g   = qk_g + (size_t)2 * NWH * NTOK * 64;
  unsigned short* hidden = (unsigned short*)(ws + R1);
  unsigned short* attno  = (unsigned short*)(ws + R2);
  unsigned short* h2     = (unsigned short*)(ws + R2);
  unsigned short* qkvwT  = (unsigned short*)(ws + R3);
  unsigned short* projwT = qkvwT + 442368;
  unsigned short* fc1wT  = projwT + 147456;
  unsigned short* fc2wT  = fc1wT + 589824;
  unsigned short* relcat = fc2wT + 589824;

  prep_kernel<<<7829, 256, 0, stream>>>(qkvw, projw, fc1w, fc2w, relh, relw,
                                        qkvwT, projwT, fc1wT, fc2wT, relcat, vT_g);
  ln1win_kernel<<<MWIN, 64, 0, stream>>>(x, ln1w, ln1b, xw);
  gemm_kernel<0><<<dim3(307, 9), 256, 0, stream>>>(xw, qkvwT, MWIN, 384, qkvb, nullptr, nullptr, qk_g, vT_g);
  attn32_kernel<<<dim3(NWH, 2), 256, 0, stream>>>(qk_g, vT_g, relcat, attno);
  gemm_kernel<1><<<dim3(307, 3), 256, 0, stream>>>(attno, projwT, MWIN, 384, projb, x, x2, nullptr, nullptr);
  ln2_kernel<<<MX, 64, 0, stream>>>(x2, ln2w, ln2b, h2);
  gemm_kernel<2><<<dim3(256, 12), 256, 0, stream>>>(h2, fc1wT, MX, 384, fc1b, nullptr, nullptr, hidden, nullptr);
  gemm_kernel<3><<<dim3(256, 3), 256, 0, stream>>>(hidden, fc2wT, MX, 1536, fc2b, x2, (float*)d_out, nullptr, nullptr);
}

// Round 14
// 340.680 us; speedup vs baseline: 1.1839x; 1.0266x over previous
//
#include <hip/hip_runtime.h>
#include <math.h>

#define DIMC 384
#define NHD  6
#define HD   64
#define WSZ  14
#define NTOK 196
#define NWIN 200
#define NWH  1200
#define MWIN 39200
#define MX   32768
#define MLPD 1536

typedef short short8 __attribute__((ext_vector_type(8)));
typedef float f32x4 __attribute__((ext_vector_type(4)));
typedef float f32x16 __attribute__((ext_vector_type(16)));

__device__ __forceinline__ unsigned short f2bf(float f) {
  unsigned int u = __float_as_uint(f);
  u = (u + 0x7fffu + ((u >> 16) & 1u)) >> 16;
  return (unsigned short)u;
}
__device__ __forceinline__ float bf2f(unsigned int u) {
  return __uint_as_float(u << 16);
}
__device__ __forceinline__ unsigned int pkbf(float a, float b) {
  unsigned int r; asm("v_cvt_pk_bf16_f32 %0, %1, %2" : "=v"(r) : "v"(a), "v"(b)); return r;
}
// tanh-GELU (|err| <= ~3e-3 abs; well under tolerance here)
__device__ __forceinline__ float gelu_t(float x) {
  float z = 1.5957691216057308f * (x + 0.044715f * x * x * x);
  float e = __expf(z);
  float th = 1.f - 2.f * __builtin_amdgcn_rcpf(e + 1.f);
  return 0.5f * x * (1.f + th);
}

typedef const __attribute__((address_space(1))) unsigned int* gptr_t;
typedef __attribute__((address_space(3))) unsigned int* lptr_t;
__device__ __forceinline__ void gload16(const unsigned short* g, unsigned short* l) {
  __builtin_amdgcn_global_load_lds((gptr_t)(const void*)g, (lptr_t)(void*)l, 16, 0, 0);
}

// ---------- merged pre: LN1+window (4 tokens/block) THEN prep segments ----------
#define LN1BLKS 9800         // 39200 tokens / 4
#define SEG0 442368          // qkvwT  (K=384,  N=1152)
#define SEG1 589824          // projwT (K=384,  N=384)
#define SEG2 1179648         // fc1wT  (K=384,  N=1536)
#define SEG3 1769472         // fc2wT  (K=1536, N=384)
#define SEG4 1773568         // relcat (4096)
#define SEG5 2003968         // vpad   (76800*3 int2 writes)
__global__ __launch_bounds__(256) void pre_kernel(
    const float* __restrict__ x, const float* __restrict__ ln1w, const float* __restrict__ ln1b,
    const float* __restrict__ qkvw, const float* __restrict__ projw,
    const float* __restrict__ fc1w, const float* __restrict__ fc2w,
    const float* __restrict__ relh, const float* __restrict__ relw,
    unsigned short* __restrict__ xw,
    unsigned short* __restrict__ qkvwT, unsigned short* __restrict__ projwT,
    unsigned short* __restrict__ fc1wT, unsigned short* __restrict__ fc2wT,
    unsigned short* __restrict__ relcat, unsigned short* __restrict__ vT) {
  const int blk = blockIdx.x;
  if (blk < LN1BLKS) {
    // LN1 + window partition, one token per 64-lane wave
    int t = blk * 4 + (threadIdx.x >> 6);
    int lane = threadIdx.x & 63;
    int win = t / NTOK, p = t - win * NTOK;
    int bb = win / 25, rem = win - bb * 25;
    int wi = rem / 5, wj = rem - wi * 5;
    int i = p / WSZ, j = p - i * WSZ;
    int r = wi * WSZ + i, c = wj * WSZ + j;
    unsigned short* o = xw + (size_t)t * DIMC;
    if (r >= 64 || c >= 64) {
      #pragma unroll
      for (int q = 0; q < 6; q++) o[lane + q * 64] = 0;
      return;
    }
    const float* xr = x + (((size_t)bb * 64 + r) * 64 + c) * DIMC;
    float v[6]; float s = 0.f, s2 = 0.f;
    #pragma unroll
    for (int q = 0; q < 6; q++) { float f = xr[lane + q * 64]; v[q] = f; s += f; s2 += f * f; }
    #pragma unroll
    for (int off = 32; off; off >>= 1) { s += __shfl_xor(s, off); s2 += __shfl_xor(s2, off); }
    float mean = s * (1.f / DIMC);
    float var  = s2 * (1.f / DIMC) - mean * mean;
    float rstd = rsqrtf(var + 1e-5f);
    #pragma unroll
    for (int q = 0; q < 6; q++) {
      int d = lane + q * 64;
      o[d] = f2bf((v[q] - mean) * rstd * ln1w[d] + ln1b[d]);
    }
    return;
  }
  int id = (blk - LN1BLKS) * 256 + threadIdx.x;
  if (id < SEG0) {
    int n = id / 384, k = id - n * 384;
    qkvwT[id] = f2bf(qkvw[(size_t)k * 1152 + n]);
  } else if (id < SEG1) {
    id -= SEG0;
    int n = id / 384, k = id - n * 384;
    projwT[id] = f2bf(projw[(size_t)k * 384 + n]);
  } else if (id < SEG2) {
    id -= SEG1;
    int n = id / 384, k = id - n * 384;
    fc1wT[id] = f2bf(fc1w[(size_t)k * 1536 + n]);
  } else if (id < SEG3) {
    id -= SEG2;
    int n = id / 1536, k = id - n * 1536;
    fc2wT[id] = f2bf(fc2w[(size_t)k * 384 + n]);
  } else if (id < SEG4) {
    id -= SEG3;
    int rc = id >> 6, d = id & 63;
    float v = 0.f;
    if (rc < 27) v = relh[rc * 64 + d] * 8.f;
    else if (rc < 54) v = relw[(rc - 27) * 64 + d] * 8.f;
    relcat[id] = f2bf(v);
  } else if (id < SEG5) {
    id -= SEG4;
    int row = id / 3, part = id - row * 3;
    *(int2*)(vT + (size_t)row * 208 + 196 + part * 4) = make_int2(0, 0);
  }
}

// ---------- LN2: 4 rows per 256-thr block, x2 in bf16 ----------
__global__ __launch_bounds__(256) void ln2_kernel(const unsigned short* __restrict__ x2b,
    const float* __restrict__ w, const float* __restrict__ b, unsigned short* __restrict__ h2) {
  int t = blockIdx.x * 4 + (threadIdx.x >> 6);
  int lane = threadIdx.x & 63;
  const unsigned short* xr = x2b + (size_t)t * DIMC;
  unsigned short* o = h2 + (size_t)t * DIMC;
  float v[6]; float s = 0.f, s2 = 0.f;
  #pragma unroll
  for (int q = 0; q < 6; q++) { float f = bf2f(xr[lane + q * 64]); v[q] = f; s += f; s2 += f * f; }
  #pragma unroll
  for (int off = 32; off; off >>= 1) { s += __shfl_xor(s, off); s2 += __shfl_xor(s2, off); }
  float mean = s * (1.f / DIMC);
  float var  = s2 * (1.f / DIMC) - mean * mean;
  float rstd = rsqrtf(var + 1e-5f);
  #pragma unroll
  for (int q = 0; q < 6; q++) {
    int d = lane + q * 64;
    o[d] = f2bf((v[q] - mean) * rstd * w[d] + b[d]);
  }
}

// ---------- bf16 MFMA GEMM: 128x128, 3-buffer counted-vmcnt pipeline, swizzled LDS,
// XCD remap. (r11/r13 proven configuration; epilogues updated for bf16 x2.) ----------
// EPI 0: qkv  -> q,k bf16 packed; v transposed scatter
// EPI 1: proj -> (acc+bias+x_f32) -> x2 bf16 packed
// EPI 2: fc1  -> bias + gelu -> hidden bf16 packed
// EPI 3: fc2  -> bias + x2(bf16) residual -> d_out fp32
template <int EPI>
__global__ __launch_bounds__(256) void gemm_kernel(
    const unsigned short* __restrict__ A, const unsigned short* __restrict__ WT,
    int Mrows, int Kd,
    const float* __restrict__ bias,
    const float* __restrict__ addinf, const unsigned short* __restrict__ addinb,
    float* __restrict__ outf, unsigned short* __restrict__ outb,
    unsigned short* __restrict__ outb2) {
  __shared__ unsigned short As[3][128 * 32];
  __shared__ unsigned short Bs[3][128 * 32];
  const int nwg = gridDim.x * gridDim.y;
  const int flat = blockIdx.y * gridDim.x + blockIdx.x;
  const int xcd = flat & 7, q_ = nwg >> 3, r_ = nwg & 7;
  const int wg = (xcd < r_ ? xcd * (q_ + 1) : r_ * (q_ + 1) + (xcd - r_) * q_) + (flat >> 3);
  const int bx = wg / gridDim.y, by = wg - bx * gridDim.y;
  const int row0 = bx * 128, col0 = by * 128;
  const int tid = threadIdx.x;
  const int l = tid & 63, wid = tid >> 6;
  const int fr = l & 15, fk = (l >> 4) * 8;
  const int wr = (wid >> 1) * 64, wc = (wid & 1) * 64;
  const int sr = l >> 2, sc = (l & 3) * 8;
  const int scs = sc ^ (((sr >> 1) & 3) << 3);
  const int rsw = ((fr >> 1) & 3) << 3;
  f32x4 acc[4][4] = {};
  const unsigned short* ap = A + (size_t)row0 * Kd;
  const unsigned short* bp = WT + (size_t)col0 * Kd;
  const int nt = Kd >> 5;

  auto stage = [&](int t, int b) {
    const int k0 = t * 32;
    #pragma unroll
    for (int j = 0; j < 2; j++) {
      int chunk = j * 4 + wid;
      gload16(ap + (size_t)(chunk * 16 + sr) * Kd + k0 + scs, &As[b][chunk * 512]);
      gload16(bp + (size_t)(chunk * 16 + sr) * Kd + k0 + scs, &Bs[b][chunk * 512]);
    }
  };
  stage(0, 0);
  stage(1, 1);
  int c = 0;
  for (int t = 0; t < nt; ++t) {
    if (t < nt - 1) asm volatile("s_waitcnt vmcnt(4)" ::: "memory");
    else            asm volatile("s_waitcnt vmcnt(0)" ::: "memory");
    __builtin_amdgcn_s_barrier();
    __builtin_amdgcn_sched_barrier(0);
    if (t + 2 < nt) stage(t + 2, (c + 2 >= 3) ? c - 1 : c + 2);
    short8 a[4], b[4];
    #pragma unroll
    for (int fi = 0; fi < 4; fi++) {
      a[fi] = *(const short8*)&As[c][(wr + fi * 16 + fr) * 32 + (fk ^ rsw)];
      b[fi] = *(const short8*)&Bs[c][(wc + fi * 16 + fr) * 32 + (fk ^ rsw)];
    }
    __builtin_amdgcn_s_setprio(1);
    #pragma unroll
    for (int fi = 0; fi < 4; fi++)
      #pragma unroll
      for (int fj = 0; fj < 4; fj++)
        acc[fi][fj] = __builtin_amdgcn_mfma_f32_16x16x32_bf16(b[fj], a[fi], acc[fi][fj], 0, 0, 0);
    __builtin_amdgcn_s_setprio(0);
    c = (c + 1 >= 3) ? 0 : c + 1;
  }
  #pragma unroll
  for (int fi = 0; fi < 4; fi++) {
    const int gr = row0 + wr + fi * 16 + fr;
    if (gr >= Mrows) continue;
    int wv_ = 0, p = 0, valid = 1; size_t pixbase = 0;
    if (EPI == 0 || EPI == 1) { wv_ = gr / NTOK; p = gr - wv_ * NTOK; }
    if (EPI == 1) {
      int bb = wv_ / 25, rem2 = wv_ - bb * 25;
      int wi = rem2 / 5, wj = rem2 - wi * 5;
      int i = p / WSZ, j = p - i * WSZ;
      int rr = wi * WSZ + i, cc = wj * WSZ + j;
      valid = (rr < 64) && (cc < 64);
      pixbase = (((size_t)bb * 64 + rr) * 64 + cc) * DIMC;
    }
    #pragma unroll
    for (int fj = 0; fj < 4; fj++) {
      const int gcb = col0 + wc + fj * 16 + (l >> 4) * 4;
      f32x4 v = acc[fi][fj];
      float4 bv = *(const float4*)&bias[gcb];
      float t0 = v[0] + bv.x, t1 = v[1] + bv.y, t2 = v[2] + bv.z, t3 = v[3] + bv.w;
      if (EPI == 0) {
        int s = gcb / 384, rem = gcb - s * 384;
        int hh = rem >> 6, d0 = gcb & 63;
        int whh = wv_ * NHD + hh;
        if (s == 0) { t0 *= 0.125f; t1 *= 0.125f; t2 *= 0.125f; t3 *= 0.125f; }
        if (s < 2) {
          *(int2*)&outb[((size_t)s * NWH + whh) * (NTOK * 64) + p * 64 + d0] =
              make_int2((int)pkbf(t0, t1), (int)pkbf(t2, t3));
        } else {
          unsigned short* vb = outb2 + ((size_t)whh * 64 + d0) * 208 + p;
          vb[0] = f2bf(t0); vb[208] = f2bf(t1); vb[416] = f2bf(t2); vb[624] = f2bf(t3);
        }
      } else if (EPI == 1) {
        if (valid) {
          size_t idx = pixbase + gcb;
          float4 ad = *(const float4*)&addinf[idx];
          *(int2*)&outb[idx] = make_int2((int)pkbf(t0 + ad.x, t1 + ad.y),
                                         (int)pkbf(t2 + ad.z, t3 + ad.w));
        }
      } else if (EPI == 2) {
        *(int2*)&outb[(size_t)gr * MLPD + gcb] =
            make_int2((int)pkbf(gelu_t(t0), gelu_t(t1)), (int)pkbf(gelu_t(t2), gelu_t(t3)));
      } else {
        size_t idx = (size_t)gr * DIMC + gcb;
        int2 adp = *(const int2*)&addinb[idx];
        unsigned int u0 = (unsigned int)adp.x, u1 = (unsigned int)adp.y;
        float4 o = make_float4(t0 + bf2f(u0 & 0xffffu), t1 + bf2f(u0 >> 16),
                               t2 + bf2f(u1 & 0xffffu), t3 + bf2f(u1 >> 16));
        *(float4*)&outf[idx] = o;
      }
    }
  }
}

// ---------- 32x32 MFMA attention: in-register P, defer-max online softmax ----------
template <bool TAIL>
__device__ __forceinline__ void attn_chunk(
    int kk, int l31, int hi,
    const unsigned short* __restrict__ kg,
    const unsigned short* __restrict__ VT,
    const short8* qf, const short8* qrel,
    f32x16& olo, f32x16& ohi_, float& m_reg, float& s_run) {
  int key = kk * 32 + l31;
  int keyc = (TAIL && key > 195) ? 195 : key;
  f32x16 S = {};
  __builtin_amdgcn_s_setprio(1);
  #pragma unroll
  for (int m = 0; m < 4; m++) {
    short8 kf = *(const short8*)(kg + (size_t)keyc * 64 + m * 16 + hi * 8);
    S = __builtin_amdgcn_mfma_f32_32x32x16_bf16(kf, qf[m], S, 0, 0, 0);
  }
  {
    int ki = keyc / 14, kj = keyc - ki * 14;
    #pragma unroll
    for (int m2 = 0; m2 < 2; m2++) {
      short8 kh;
      #pragma unroll
      for (int j = 0; j < 8; j++) {
        int cc = m2 * 16 + hi * 8 + j;
        kh[j] = (short)((cc == ki || cc == 14 + kj) ? 0x3F80 : 0);
      }
      S = __builtin_amdgcn_mfma_f32_32x32x16_bf16(kh, qrel[m2], S, 0, 0, 0);
    }
  }
  __builtin_amdgcn_s_setprio(0);
  float pmax = -3e38f;
  #pragma unroll
  for (int r = 0; r < 16; r++) {
    if (TAIL) {
      int krow = kk * 32 + (r & 3) + 8 * (r >> 2) + 4 * hi;
      if (krow >= 196) S[r] = -3e38f;
    }
    pmax = fmaxf(pmax, S[r]);
  }
  pmax = fmaxf(pmax, __shfl_xor(pmax, 32));
  if (__any(pmax > m_reg + 8.f)) {
    float m_new = fmaxf(m_reg, pmax);
    float fac = __expf(m_reg - m_new);
    m_reg = m_new;
    s_run *= fac;
    #pragma unroll
    for (int r = 0; r < 16; r++) {
      int qr = (r & 3) + 8 * (r >> 2) + 4 * hi;
      float fr_ = __shfl(fac, qr);
      olo[r] *= fr_; ohi_[r] *= fr_;
    }
  }
  float psum = 0.f;
  #pragma unroll
  for (int r = 0; r < 16; r++) { S[r] = __expf(S[r] - m_reg); psum += S[r]; }
  s_run += psum;
  unsigned int pk[8];
  #pragma unroll
  for (int t = 0; t < 8; t++) pk[t] = pkbf(S[2 * t], S[2 * t + 1]);
  #pragma unroll
  for (int m2 = 0; m2 < 2; m2++) {
    int b_ = m2 * 4;
    unsigned int x0 = (unsigned int)__shfl_xor((int)pk[b_ + 0], 32);
    unsigned int x1 = (unsigned int)__shfl_xor((int)pk[b_ + 1], 32);
    unsigned int x2 = (unsigned int)__shfl_xor((int)pk[b_ + 2], 32);
    unsigned int x3 = (unsigned int)__shfl_xor((int)pk[b_ + 3], 32);
    unsigned int au[4];
    au[0] = hi ? x2 : pk[b_ + 0];
    au[1] = hi ? x3 : pk[b_ + 1];
    au[2] = hi ? pk[b_ + 2] : x0;
    au[3] = hi ? pk[b_ + 3] : x1;
    short8 pa; __builtin_memcpy(&pa, au, 16);
    int kb = kk * 32 + m2 * 16 + hi * 8;
    if (TAIL && kb > 208) kb = 208;
    short8 vblo = *(const short8*)&VT[l31 * 216 + kb];
    short8 vbhi = *(const short8*)&VT[(32 + l31) * 216 + kb];
    __builtin_amdgcn_s_setprio(1);
    olo  = __builtin_amdgcn_mfma_f32_32x32x16_bf16(pa, vblo, olo, 0, 0, 0);
    ohi_ = __builtin_amdgcn_mfma_f32_32x32x16_bf16(pa, vbhi, ohi_, 0, 0, 0);
    __builtin_amdgcn_s_setprio(0);
  }
}

__global__ __launch_bounds__(256) void attn32_kernel(
    const unsigned short* __restrict__ qk_g,
    const unsigned short* __restrict__ vT_g,
    const unsigned short* __restrict__ relcat,
    unsigned short* __restrict__ attnout) {
  __shared__ __align__(16) unsigned short VT[64 * 216];
  __shared__ __align__(16) unsigned short RELB[4][2048];
  const int wh = blockIdx.x, y = blockIdx.y;
  const int w = wh / NHD, h = wh - w * NHD;
  const int tid = threadIdx.x;
  const unsigned short* vrow = vT_g + (size_t)wh * 64 * 208;
  for (int e = tid; e < 64 * 27; e += 256) {
    int d = e / 27, c = e - d * 27;
    int4 val = {0, 0, 0, 0};
    if (c < 26) val = *(const int4*)(vrow + d * 208 + c * 8);
    *(int4*)&VT[d * 216 + c * 8] = val;
  }
  __syncthreads();
  const int l = tid & 63, wv = tid >> 6;
  const int l31 = l & 31, hi = l >> 5;
  unsigned short* RB = &RELB[wv][0];
  const unsigned short* qg = qk_g + (size_t)wh * (NTOK * 64);
  const unsigned short* kg = qk_g + (size_t)(NWH + wh) * (NTOK * 64);

  const int tbeg = y ? 4 : 0, tend = y ? 7 : 4;
  for (int tile = tbeg + wv; tile < tend; tile += 4) {
    const int q0 = tile * 32;
    int qrow = q0 + l31; if (qrow > 195) qrow = 195;
    short8 qf[4];
    #pragma unroll
    for (int m = 0; m < 4; m++)
      qf[m] = *(const short8*)(qg + (size_t)qrow * 64 + m * 16 + hi * 8);
    #pragma unroll
    for (int rt = 0; rt < 2; rt++) {
      f32x16 cr = {};
      __builtin_amdgcn_s_setprio(1);
      #pragma unroll
      for (int m = 0; m < 4; m++) {
        short8 af = *(const short8*)(relcat + (rt * 32 + l31) * 64 + m * 16 + hi * 8);
        cr = __builtin_amdgcn_mfma_f32_32x32x16_bf16(af, qf[m], cr, 0, 0, 0);
      }
      __builtin_amdgcn_s_setprio(0);
      #pragma unroll
      for (int t = 0; t < 8; t++) {
        int rr = rt * 32 + ((2 * t) & 3) + 8 * (t >> 1) + 4 * hi;
        *(unsigned int*)&RB[l31 * 64 + rr] = pkbf(cr[2 * t], cr[2 * t + 1]);
      }
    }
    __builtin_amdgcn_wave_barrier();
    int qi = qrow / 14, qj = qrow - qi * 14;
    short8 qrel[2];
    #pragma unroll
    for (int m2 = 0; m2 < 2; m2++)
      #pragma unroll
      for (int j = 0; j < 8; j++) {
        int cc = m2 * 16 + hi * 8 + j;
        unsigned short vv = 0;
        if (cc < 14) vv = RB[l31 * 64 + (qi - cc + 13)];
        else if (cc < 28) vv = RB[l31 * 64 + 27 + (qj - (cc - 14) + 13)];
        qrel[m2][j] = (short)vv;
      }
    __builtin_amdgcn_wave_barrier();
    f32x16 olo = {}, ohi_ = {};
    float m_reg = -3e38f, s_run = 0.f;
    for (int kk = 0; kk < 6; kk++)
      attn_chunk<false>(kk, l31, hi, kg, VT, qf, qrel, olo, ohi_, m_reg, s_run);
    attn_chunk<true>(6, l31, hi, kg, VT, qf, qrel, olo, ohi_, m_reg, s_run);
    s_run += __shfl_xor(s_run, 32);
    float inv = 1.f / s_run;
    #pragma unroll
    for (int r = 0; r < 16; r++) {
      int qr = (r & 3) + 8 * (r >> 2) + 4 * hi;
      float ir = __shfl(inv, qr);
      int tok = q0 + qr;
      if (tok < 196) {
        size_t base = ((size_t)w * NTOK + tok) * DIMC + h * 64;
        attnout[base + l31] = f2bf(olo[r] * ir);
        attnout[base + 32 + l31] = f2bf(ohi_[r] * ir);
      }
    }
  }
}

extern "C" void kernel_launch(void* const* d_in, const int* in_sizes, int n_in,
                              void* d_out, int out_size, void* d_ws, size_t ws_size,
                              hipStream_t stream) {
  const float* x     = (const float*)d_in[0];
  const float* ln1w  = (const float*)d_in[1];
  const float* ln1b  = (const float*)d_in[2];
  const float* qkvw  = (const float*)d_in[3];
  const float* qkvb  = (const float*)d_in[4];
  const float* projw = (const float*)d_in[5];
  const float* projb = (const float*)d_in[6];
  const float* relh  = (const float*)d_in[7];
  const float* relw  = (const float*)d_in[8];
  const float* ln2w  = (const float*)d_in[9];
  const float* ln2b  = (const float*)d_in[10];
  const float* fc1w  = (const float*)d_in[11];
  const float* fc1b  = (const float*)d_in[12];
  const float* fc2w  = (const float*)d_in[13];
  const float* fc2b  = (const float*)d_in[14];

  // R0: xw bf16 -> x2 bf16 (25.2 MB)
  // R1: qk + vT bf16 -> hidden bf16
  // R2: attno bf16 -> h2 bf16
  // R3: transposed bf16 weights + relcat
  const size_t R0 = 0;
  const size_t R1 = R0 + 50331648;
  const size_t R2 = R1 + 100663296;
  const size_t R3 = R2 + 30408704;
  const size_t NEED = R3 + 3547136;
  if (ws_size < NEED) return;
  char* ws = (char*)d_ws;
  unsigned short* xw     = (unsigned short*)(ws + R0);
  unsigned short* x2b    = (unsigned short*)(ws + R0);
  unsigned short* qk_g   = (unsigned short*)(ws + R1);
  unsigned short* vT_g   = qk_g + (size_t)2 * NWH * NTOK * 64;
  unsigned short* hidden = (unsigned short*)(ws + R1);
  unsigned short* attno  = (unsigned short*)(ws + R2);
  unsigned short* h2     = (unsigned short*)(ws + R2);
  unsigned short* qkvwT  = (unsigned short*)(ws + R3);
  unsigned short* projwT = qkvwT + 442368;
  unsigned short* fc1wT  = projwT + 147456;
  unsigned short* fc2wT  = fc1wT + 589824;
  unsigned short* relcat = fc2wT + 589824;

  pre_kernel<<<LN1BLKS + 7828, 256, 0, stream>>>(x, ln1w, ln1b, qkvw, projw, fc1w, fc2w,
                                                 relh, relw, xw, qkvwT, projwT, fc1wT,
                                                 fc2wT, relcat, vT_g);
  gemm_kernel<0><<<dim3(307, 9), 256, 0, stream>>>(xw, qkvwT, MWIN, 384, qkvb,
                                                   nullptr, nullptr, nullptr, qk_g, vT_g);
  attn32_kernel<<<dim3(NWH, 2), 256, 0, stream>>>(qk_g, vT_g, relcat, attno);
  gemm_kernel<1><<<dim3(307, 3), 256, 0, stream>>>(attno, projwT, MWIN, 384, projb,
                                                   x, nullptr, nullptr, x2b, nullptr);
  ln2_kernel<<<8192, 256, 0, stream>>>(x2b, ln2w, ln2b, h2);
  gemm_kernel<2><<<dim3(256, 12), 256, 0, stream>>>(h2, fc1wT, MX, 384, fc1b,
                                                    nullptr, nullptr, nullptr, hidden, nullptr);
  gemm_kernel<3><<<dim3(256, 3), 256, 0, stream>>>(hidden, fc2wT, MX, 1536, fc2b,
                                                   nullptr, x2b, (float*)d_out, nullptr, nullptr);
}